// Round 8
// baseline (558.608 us; speedup 1.0000x reference)
//
#include <hip/hip_runtime.h>

#define B_ 128
#define T_ 128
#define I_ 1024
#define O_ 1024
#define M_ (B_*T_)          // 16384 rows of h
#define NOUT (M_*O_)        // 16777216 spike outputs, loss at index NOUT

typedef __attribute__((ext_vector_type(8))) short short8;   // 8 bf16 = 4 VGPR
typedef __attribute__((ext_vector_type(4))) float floatx4;  // MFMA acc

// async global->LDS, 16B per lane. LDS dest = wave-uniform base + lane*16.
__device__ __forceinline__ void gld_lds16(const void* g, void* l) {
    __builtin_amdgcn_global_load_lds((const __attribute__((address_space(1))) void*)g,
                                     (__attribute__((address_space(3))) void*)l,
                                     16, 0, 0);
}

// Workgroup barrier waiting ONLY on LDS ops (lgkmcnt(0)); does NOT drain vmcnt.
__device__ __forceinline__ void barrier_lds_only() {
    asm volatile("" ::: "memory");
    __builtin_amdgcn_s_waitcnt(0xC07F);
    __builtin_amdgcn_s_barrier();
    asm volatile("" ::: "memory");
}

// Dekker-style exact 3-way bf16 split by truncation.
__device__ __forceinline__ void split3(float x, unsigned short& h,
                                       unsigned short& m, unsigned short& l) {
    unsigned int b0 = __float_as_uint(x);
    h = (unsigned short)(b0 >> 16);
    float r1 = x - __uint_as_float(b0 & 0xFFFF0000u);
    unsigned int b1 = __float_as_uint(r1);
    m = (unsigned short)(b1 >> 16);
    float r2 = r1 - __uint_as_float(b1 & 0xFFFF0000u);
    l = (unsigned short)(__float_as_uint(r2) >> 16);
}

// ---------------------------------------------------------------------------
// split_x: x [M,K] f32 -> 3 bf16 planes, same layout. Pure memory pass.
// ---------------------------------------------------------------------------
__global__ __launch_bounds__(256) void split_x(const float* __restrict__ X,
                                               unsigned short* __restrict__ Xh,
                                               unsigned short* __restrict__ Xm,
                                               unsigned short* __restrict__ Xl) {
    size_t base = ((size_t)blockIdx.x * 256 + threadIdx.x) * 4;
    float4 v = *(const float4*)(X + base);
    ushort4 hh, mm, ll;
    split3(v.x, hh.x, mm.x, ll.x);
    split3(v.y, hh.y, mm.y, ll.y);
    split3(v.z, hh.z, mm.z, ll.z);
    split3(v.w, hh.w, mm.w, ll.w);
    *(ushort4*)(Xh + base) = hh;
    *(ushort4*)(Xm + base) = mm;
    *(ushort4*)(Xl + base) = ll;
}

// ---------------------------------------------------------------------------
// split_wt: w [K][N] f32 -> three TRANSPOSED bf16 planes wt_p[N][K].
// ---------------------------------------------------------------------------
__global__ __launch_bounds__(256) void split_wt(const float* __restrict__ W,
                                                unsigned short* __restrict__ WTh,
                                                unsigned short* __restrict__ WTm,
                                                unsigned short* __restrict__ WTl) {
    __shared__ float t[64][65];
    const int tid = threadIdx.x;
    const int tx = tid & 63, ty4 = tid >> 6;
    const int r0 = blockIdx.x * 64, c0 = blockIdx.y * 64;
#pragma unroll
    for (int j = 0; j < 16; ++j) {
        int row = j * 4 + ty4;
        t[row][tx] = W[(size_t)(r0 + row) * O_ + c0 + tx];
    }
    __syncthreads();
#pragma unroll
    for (int j = 0; j < 16; ++j) {
        int i = j * 4 + ty4;
        float v = t[tx][i];
        unsigned short h, m, l;
        split3(v, h, m, l);
        size_t off = (size_t)(c0 + i) * I_ + r0 + tx;
        WTh[off] = h; WTm[off] = m; WTl[off] = l;
    }
}

// ---------------------------------------------------------------------------
// h = x @ w, all-bf16 split MFMA (r6 structure: XOR-swizzled LDS, 0 bank
// conflicts, MfmaUtil ~65%).
// ---------------------------------------------------------------------------
__global__ __launch_bounds__(256, 3) void gemm_h_mfma(
        const unsigned short* __restrict__ Xh, const unsigned short* __restrict__ Xm,
        const unsigned short* __restrict__ Xl, const unsigned short* __restrict__ WTh,
        const unsigned short* __restrict__ WTm, const unsigned short* __restrict__ WTl,
        float* __restrict__ H) {
    const int K = I_, N = O_;
    __shared__ unsigned short P[6][128 * 32];   // 6 planes x 8 KB = 48 KB

    const int tid = threadIdx.x;
    const int lane = tid & 63;
    const int wid = tid >> 6;
    const int wrow = wid >> 1, wcol = wid & 1;
    const int l15 = lane & 15, quad = lane >> 4;
    const int bm = blockIdx.x * 128, bn = blockIdx.y * 128;

    const int srow = tid >> 2, sch = tid & 3;
    const int schg = sch ^ ((srow >> 1) & 3);
    const unsigned short* gsrc[6];
    gsrc[0] = Xh  + (size_t)(bm + srow) * K + schg * 8;
    gsrc[1] = Xm  + (size_t)(bm + srow) * K + schg * 8;
    gsrc[2] = Xl  + (size_t)(bm + srow) * K + schg * 8;
    gsrc[3] = WTh + (size_t)(bn + srow) * K + schg * 8;
    gsrc[4] = WTm + (size_t)(bn + srow) * K + schg * 8;
    gsrc[5] = WTl + (size_t)(bn + srow) * K + schg * 8;

    floatx4 acc[4][4];
#pragma unroll
    for (int mt = 0; mt < 4; ++mt)
#pragma unroll
        for (int nt = 0; nt < 4; ++nt) acc[mt][nt] = (floatx4)(0.f);

    for (int kt = 0; kt < 32; ++kt) {
        const int k0 = kt * 32;
        __syncthreads();
#pragma unroll
        for (int p = 0; p < 6; ++p) {
            unsigned short* dst = (unsigned short*)P + p * 4096 + tid * 8;
            gld_lds16(gsrc[p] + k0, dst);
            gld_lds16(gsrc[p] + (size_t)64 * K + k0, dst + 2048);
        }
        __syncthreads();

        short8 Af[3][4];
#pragma unroll
        for (int pa = 0; pa < 3; ++pa)
#pragma unroll
            for (int mt = 0; mt < 4; ++mt) {
                int row = wrow * 64 + mt * 16 + l15;
                int chk = quad ^ ((row >> 1) & 3);
                Af[pa][mt] = *(const short8*)((const unsigned short*)P + pa * 4096 + row * 32 + chk * 8);
            }
#pragma unroll
        for (int pb = 0; pb < 3; ++pb) {
            short8 Bf[4];
#pragma unroll
            for (int nt = 0; nt < 4; ++nt) {
                int col = wcol * 64 + nt * 16 + l15;
                int chk = quad ^ ((col >> 1) & 3);
                Bf[nt] = *(const short8*)((const unsigned short*)P + (3 + pb) * 4096 + col * 32 + chk * 8);
            }
#pragma unroll
            for (int nt = 0; nt < 4; ++nt)
#pragma unroll
                for (int mt = 0; mt < 4; ++mt) {
                    acc[mt][nt] = __builtin_amdgcn_mfma_f32_16x16x32_bf16(Af[0][mt], Bf[nt], acc[mt][nt], 0, 0, 0);
                    acc[mt][nt] = __builtin_amdgcn_mfma_f32_16x16x32_bf16(Af[1][mt], Bf[nt], acc[mt][nt], 0, 0, 0);
                    if (pb < 2)
                        acc[mt][nt] = __builtin_amdgcn_mfma_f32_16x16x32_bf16(Af[2][mt], Bf[nt], acc[mt][nt], 0, 0, 0);
                }
        }
    }

#pragma unroll
    for (int mt = 0; mt < 4; ++mt)
#pragma unroll
        for (int nt = 0; nt < 4; ++nt) {
            int grow = bm + wrow * 64 + mt * 16 + quad * 4;
            int gcol = bn + wcol * 64 + nt * 16 + l15;
            float* hp = H + (size_t)grow * N + gcol;
#pragma unroll
            for (int r = 0; r < 4; ++r) hp[(size_t)r * N] = acc[mt][nt][r];
        }
}

// ---------------------------------------------------------------------------
// d = w^T w   (fp32 exact-class).
// ---------------------------------------------------------------------------
__global__ __launch_bounds__(256) void gemm_wtw(const float* __restrict__ W,
                                                float* __restrict__ D) {
    const int K = I_, N = O_;
    __shared__ float As[32][68];
    __shared__ float Bs[32][68];
    const int tid = threadIdx.x;
    const int tx = tid & 15, ty = tid >> 4;
    const int bj = blockIdx.x * 64, bo = blockIdx.y * 64;
    const int lr = tid >> 4;
    const int lc = (tid & 15) << 2;

    float acc[4][4];
#pragma unroll
    for (int m = 0; m < 4; m++)
#pragma unroll
        for (int n = 0; n < 4; n++) acc[m][n] = 0.f;

    for (int k0 = 0; k0 < K; k0 += 32) {
        float4 a0 = *(const float4*)(W + (size_t)(k0 + lr) * N + bj + lc);
        float4 a1 = *(const float4*)(W + (size_t)(k0 + lr + 16) * N + bj + lc);
        float4 b0 = *(const float4*)(W + (size_t)(k0 + lr) * N + bo + lc);
        float4 b1 = *(const float4*)(W + (size_t)(k0 + lr + 16) * N + bo + lc);
        __syncthreads();
        *(float4*)&As[lr][lc] = a0; *(float4*)&As[lr + 16][lc] = a1;
        *(float4*)&Bs[lr][lc] = b0; *(float4*)&Bs[lr + 16][lc] = b1;
        __syncthreads();
#pragma unroll
        for (int k = 0; k < 32; ++k) {
            float4 av = *(const float4*)&As[k][ty * 4];
            float4 bv = *(const float4*)&Bs[k][tx * 4];
            float am[4] = {av.x, av.y, av.z, av.w};
            float bb[4] = {bv.x, bv.y, bv.z, bv.w};
#pragma unroll
            for (int m = 0; m < 4; m++)
#pragma unroll
                for (int n = 0; n < 4; n++) acc[m][n] += am[m] * bb[n];
        }
    }
#pragma unroll
    for (int m = 0; m < 4; m++) {
        float4 v = make_float4(acc[m][0], acc[m][1], acc[m][2], acc[m][3]);
        *(float4*)(D + (size_t)(bj + ty * 4 + m) * N + bo + tx * 4) = v;
    }
}

// inv_norm[o] = 1/(d[o][o] + 1e-8); also zero the spike counter.
__global__ void colnorm_diag(const float* __restrict__ D, float* __restrict__ invn,
                             unsigned int* __restrict__ counter) {
    int o = blockIdx.x * 256 + threadIdx.x;
    if (o == 0) *counter = 0u;
    invn[o] = 1.0f / (D[(size_t)o * O_ + o] + 1e-8f);
}

// ---------------------------------------------------------------------------
// Sequential scan. r8: latency-optimized gather. n is BLOCK-UNIFORM, so the
// (u < n) guards are uniform s_cbranch. Three phases per 16-chunk:
//  (1) read all 16 indices (independent ds_reads, clamped addr, ONE lgkm wait)
//  (2) issue all <=16 gather loads back-to-back (in flight together)
//  (3) accumulate (one vm wait at first use).
// Typical step (n~9): ONE lds round trip + ONE vmem round trip, vs r7's
// 3-6 chained trips (4-batches + singles) = the 3700cyc/step mystery.
// ---------------------------------------------------------------------------
__global__ __launch_bounds__(256) void scan_kernel(const float* __restrict__ h,
                                                   const float* __restrict__ d,
                                                   const float* __restrict__ invn,
                                                   const float* __restrict__ bias,
                                                   const float* __restrict__ beta,
                                                   float* __restrict__ out,
                                                   unsigned int* __restrict__ spike_count) {
    __shared__ int lst[2][O_];
    __shared__ int cnt[T_ + 1];
    __shared__ unsigned int red[256];

    const int tid = threadIdx.x;
    const int lane = tid & 63;
    const int b = blockIdx.x;
    const int o4 = tid * 4;
    const float betav = beta[0];
    const float omb = 1.0f - betav;

    const float4 invn4 = *(const float4*)(invn + o4);
    const float4 b4 = *(const float4*)(bias + o4);
    float4 mem4 = make_float4(0.f, 0.f, 0.f, 0.f);

    for (int i = tid; i <= T_; i += 256) cnt[i] = 0;
    unsigned int local_count = 0;
    const float* hb = h + (size_t)b * T_ * O_;
    float* ob = out + (size_t)b * T_ * O_;
    const unsigned long long below = (lane == 63) ? 0xFFFFFFFFFFFFFFFFull >> 1
                                                  : ((1ull << lane) - 1ull);

    float4 hcur = *(const float4*)(hb + o4);   // t = 0
    __syncthreads();

    for (int t = 0; t < T_; ++t) {
        const int p = t & 1, q = p ^ 1;
        const int n = cnt[t];                  // block-uniform

        float4 hnext = make_float4(0.f, 0.f, 0.f, 0.f);
        if (t + 1 < T_) hnext = *(const float4*)(hb + (size_t)(t + 1) * O_ + o4);

        float4 rst = make_float4(0.f, 0.f, 0.f, 0.f);
        for (int i0 = 0; i0 < n; i0 += 16) {
            // phase 1: all indices (clamped -> unconditional independent ds_reads)
            int jj[16];
#pragma unroll
            for (int u = 0; u < 16; ++u) {
                int idx = (i0 + u < n) ? (i0 + u) : 0;
                jj[u] = lst[p][idx];
            }
            // phase 2: issue all loads (uniform guards -> s_cbranch, loads
            // stay in flight together)
            float4 v[16];
#pragma unroll
            for (int u = 0; u < 16; ++u)
                if (i0 + u < n)
                    v[u] = *(const float4*)(d + (size_t)jj[u] * O_ + o4);
            // phase 3: accumulate (single vm wait at first use)
#pragma unroll
            for (int u = 0; u < 16; ++u)
                if (i0 + u < n) {
                    rst.x += v[u].x; rst.y += v[u].y;
                    rst.z += v[u].z; rst.w += v[u].w;
                }
        }

        mem4.x = (mem4.x - rst.x) * betav + hcur.x * omb;
        mem4.y = (mem4.y - rst.y) * betav + hcur.y * omb;
        mem4.z = (mem4.z - rst.z) * betav + hcur.z * omb;
        mem4.w = (mem4.w - rst.w) * betav + hcur.w * omb;

        const int s[4] = {(mem4.x * invn4.x - b4.x) > 0.0f,
                          (mem4.y * invn4.y - b4.y) > 0.0f,
                          (mem4.z * invn4.z - b4.z) > 0.0f,
                          (mem4.w * invn4.w - b4.w) > 0.0f};

        float4 sv = make_float4(s[0] ? 1.f : 0.f, s[1] ? 1.f : 0.f,
                                s[2] ? 1.f : 0.f, s[3] ? 1.f : 0.f);
        *(float4*)(ob + (size_t)t * O_ + o4) = sv;
        local_count += (unsigned)(s[0] + s[1] + s[2] + s[3]);

        // ballot-aggregated appends into lst[q] / cnt[t+1]
#pragma unroll
        for (int u = 0; u < 4; ++u) {
            unsigned long long mask = __ballot(s[u]);
            int base = 0;
            if (lane == 0 && mask) base = atomicAdd(&cnt[t + 1], __popcll(mask));
            base = __shfl(base, 0, 64);
            if (s[u]) lst[q][base + __popcll(mask & below)] = o4 + u;
        }

        barrier_lds_only();
        hcur = hnext;
    }

    red[tid] = local_count;
    __syncthreads();
    for (int st = 128; st > 0; st >>= 1) {
        if (tid < st) red[tid] += red[tid + st];
        __syncthreads();
    }
    if (tid == 0) atomicAdd(spike_count, red[0]);
}

__global__ void finalize_loss(const unsigned int* __restrict__ spike_count,
                              float* __restrict__ loss_out) {
    *loss_out = 0.5f * ((float)(*spike_count) / 16777216.0f);
}

// ---------------------------------------------------------------------------
extern "C" void kernel_launch(void* const* d_in, const int* in_sizes, int n_in,
                              void* d_out, int out_size, void* d_ws, size_t ws_size,
                              hipStream_t stream) {
    const float* x    = (const float*)d_in[0];   // [B,T,I]
    const float* w    = (const float*)d_in[1];   // [I,O]
    const float* beta = (const float*)d_in[2];   // [1]
    const float* bias = (const float*)d_in[3];   // [O]
    float* out = (float*)d_out;                  // NOUT spikes + 1 loss

    // workspace layout (~170 MB)
    char* ws = (char*)d_ws;
    float* h    = (float*)ws;                                         // 64 MiB
    float* dmat = (float*)(ws + (size_t)67108864);                    // 4 MiB
    float* invn = (float*)(ws + (size_t)71303168);                    // 4 KiB
    unsigned int* cntp = (unsigned int*)(ws + (size_t)71307264);      // 4 KiB
    unsigned short* wt_h = (unsigned short*)(ws + (size_t)71311360);  // 2 MiB
    unsigned short* wt_m = (unsigned short*)(ws + (size_t)73408512);  // 2 MiB
    unsigned short* wt_l = (unsigned short*)(ws + (size_t)75505664);  // 2 MiB
    unsigned short* x_h  = (unsigned short*)(ws + (size_t)77602816);  // 32 MiB
    unsigned short* x_m  = (unsigned short*)(ws + (size_t)111157248); // 32 MiB
    unsigned short* x_l  = (unsigned short*)(ws + (size_t)144711680); // 32 MiB

    split_x<<<M_ * I_ / 1024, 256, 0, stream>>>(x, x_h, x_m, x_l);
    split_wt<<<dim3(I_ / 64, O_ / 64), 256, 0, stream>>>(w, wt_h, wt_m, wt_l);
    gemm_h_mfma<<<dim3(M_ / 128, O_ / 128), 256, 0, stream>>>(x_h, x_m, x_l,
                                                              wt_h, wt_m, wt_l, h);
    gemm_wtw<<<dim3(O_ / 64, O_ / 64), 256, 0, stream>>>(w, dmat);
    colnorm_diag<<<O_ / 256, 256, 0, stream>>>(dmat, invn, cntp);
    scan_kernel<<<B_, 256, 0, stream>>>(h, dmat, invn, bias, beta, out, cntp);
    finalize_loss<<<1, 1, 0, stream>>>(cntp, out + (size_t)NOUT);
}

// Round 9
// 545.280 us; speedup vs baseline: 1.0244x; 1.0244x over previous
//
#include <hip/hip_runtime.h>

#define B_ 128
#define T_ 128
#define I_ 1024
#define O_ 1024
#define M_ (B_*T_)          // 16384 rows of h
#define NOUT (M_*O_)        // 16777216 spike outputs, loss at index NOUT
#define ZROW O_             // index of the all-zero padding row appended to d

typedef __attribute__((ext_vector_type(8))) short short8;   // 8 bf16 = 4 VGPR
typedef __attribute__((ext_vector_type(4))) float floatx4;  // MFMA acc

// async global->LDS, 16B per lane. LDS dest = wave-uniform base + lane*16.
__device__ __forceinline__ void gld_lds16(const void* g, void* l) {
    __builtin_amdgcn_global_load_lds((const __attribute__((address_space(1))) void*)g,
                                     (__attribute__((address_space(3))) void*)l,
                                     16, 0, 0);
}

// Workgroup barrier waiting ONLY on LDS ops (lgkmcnt(0)); does NOT drain vmcnt.
__device__ __forceinline__ void barrier_lds_only() {
    asm volatile("" ::: "memory");
    __builtin_amdgcn_s_waitcnt(0xC07F);
    __builtin_amdgcn_s_barrier();
    asm volatile("" ::: "memory");
}

// Dekker-style exact 3-way bf16 split by truncation.
__device__ __forceinline__ void split3(float x, unsigned short& h,
                                       unsigned short& m, unsigned short& l) {
    unsigned int b0 = __float_as_uint(x);
    h = (unsigned short)(b0 >> 16);
    float r1 = x - __uint_as_float(b0 & 0xFFFF0000u);
    unsigned int b1 = __float_as_uint(r1);
    m = (unsigned short)(b1 >> 16);
    float r2 = r1 - __uint_as_float(b1 & 0xFFFF0000u);
    l = (unsigned short)(__float_as_uint(r2) >> 16);
}

// ---------------------------------------------------------------------------
// split_x: x [M,K] f32 -> 3 bf16 planes, same layout. Pure memory pass.
// ---------------------------------------------------------------------------
__global__ __launch_bounds__(256) void split_x(const float* __restrict__ X,
                                               unsigned short* __restrict__ Xh,
                                               unsigned short* __restrict__ Xm,
                                               unsigned short* __restrict__ Xl) {
    size_t base = ((size_t)blockIdx.x * 256 + threadIdx.x) * 4;
    float4 v = *(const float4*)(X + base);
    ushort4 hh, mm, ll;
    split3(v.x, hh.x, mm.x, ll.x);
    split3(v.y, hh.y, mm.y, ll.y);
    split3(v.z, hh.z, mm.z, ll.z);
    split3(v.w, hh.w, mm.w, ll.w);
    *(ushort4*)(Xh + base) = hh;
    *(ushort4*)(Xm + base) = mm;
    *(ushort4*)(Xl + base) = ll;
}

// ---------------------------------------------------------------------------
// split_wt: w [K][N] f32 -> three TRANSPOSED bf16 planes wt_p[N][K].
// ---------------------------------------------------------------------------
__global__ __launch_bounds__(256) void split_wt(const float* __restrict__ W,
                                                unsigned short* __restrict__ WTh,
                                                unsigned short* __restrict__ WTm,
                                                unsigned short* __restrict__ WTl) {
    __shared__ float t[64][65];
    const int tid = threadIdx.x;
    const int tx = tid & 63, ty4 = tid >> 6;
    const int r0 = blockIdx.x * 64, c0 = blockIdx.y * 64;
#pragma unroll
    for (int j = 0; j < 16; ++j) {
        int row = j * 4 + ty4;
        t[row][tx] = W[(size_t)(r0 + row) * O_ + c0 + tx];
    }
    __syncthreads();
#pragma unroll
    for (int j = 0; j < 16; ++j) {
        int i = j * 4 + ty4;
        float v = t[tx][i];
        unsigned short h, m, l;
        split3(v, h, m, l);
        size_t off = (size_t)(c0 + i) * I_ + r0 + tx;
        WTh[off] = h; WTm[off] = m; WTl[off] = l;
    }
}

// ---------------------------------------------------------------------------
// h = x @ w, all-bf16 split MFMA (r6 structure: XOR-swizzled LDS, 0 bank
// conflicts, MfmaUtil ~65%).
// ---------------------------------------------------------------------------
__global__ __launch_bounds__(256, 3) void gemm_h_mfma(
        const unsigned short* __restrict__ Xh, const unsigned short* __restrict__ Xm,
        const unsigned short* __restrict__ Xl, const unsigned short* __restrict__ WTh,
        const unsigned short* __restrict__ WTm, const unsigned short* __restrict__ WTl,
        float* __restrict__ H) {
    const int K = I_, N = O_;
    __shared__ unsigned short P[6][128 * 32];   // 6 planes x 8 KB = 48 KB

    const int tid = threadIdx.x;
    const int lane = tid & 63;
    const int wid = tid >> 6;
    const int wrow = wid >> 1, wcol = wid & 1;
    const int l15 = lane & 15, quad = lane >> 4;
    const int bm = blockIdx.x * 128, bn = blockIdx.y * 128;

    const int srow = tid >> 2, sch = tid & 3;
    const int schg = sch ^ ((srow >> 1) & 3);
    const unsigned short* gsrc[6];
    gsrc[0] = Xh  + (size_t)(bm + srow) * K + schg * 8;
    gsrc[1] = Xm  + (size_t)(bm + srow) * K + schg * 8;
    gsrc[2] = Xl  + (size_t)(bm + srow) * K + schg * 8;
    gsrc[3] = WTh + (size_t)(bn + srow) * K + schg * 8;
    gsrc[4] = WTm + (size_t)(bn + srow) * K + schg * 8;
    gsrc[5] = WTl + (size_t)(bn + srow) * K + schg * 8;

    floatx4 acc[4][4];
#pragma unroll
    for (int mt = 0; mt < 4; ++mt)
#pragma unroll
        for (int nt = 0; nt < 4; ++nt) acc[mt][nt] = (floatx4)(0.f);

    for (int kt = 0; kt < 32; ++kt) {
        const int k0 = kt * 32;
        __syncthreads();
#pragma unroll
        for (int p = 0; p < 6; ++p) {
            unsigned short* dst = (unsigned short*)P + p * 4096 + tid * 8;
            gld_lds16(gsrc[p] + k0, dst);
            gld_lds16(gsrc[p] + (size_t)64 * K + k0, dst + 2048);
        }
        __syncthreads();

        short8 Af[3][4];
#pragma unroll
        for (int pa = 0; pa < 3; ++pa)
#pragma unroll
            for (int mt = 0; mt < 4; ++mt) {
                int row = wrow * 64 + mt * 16 + l15;
                int chk = quad ^ ((row >> 1) & 3);
                Af[pa][mt] = *(const short8*)((const unsigned short*)P + pa * 4096 + row * 32 + chk * 8);
            }
#pragma unroll
        for (int pb = 0; pb < 3; ++pb) {
            short8 Bf[4];
#pragma unroll
            for (int nt = 0; nt < 4; ++nt) {
                int col = wcol * 64 + nt * 16 + l15;
                int chk = quad ^ ((col >> 1) & 3);
                Bf[nt] = *(const short8*)((const unsigned short*)P + (3 + pb) * 4096 + col * 32 + chk * 8);
            }
#pragma unroll
            for (int nt = 0; nt < 4; ++nt)
#pragma unroll
                for (int mt = 0; mt < 4; ++mt) {
                    acc[mt][nt] = __builtin_amdgcn_mfma_f32_16x16x32_bf16(Af[0][mt], Bf[nt], acc[mt][nt], 0, 0, 0);
                    acc[mt][nt] = __builtin_amdgcn_mfma_f32_16x16x32_bf16(Af[1][mt], Bf[nt], acc[mt][nt], 0, 0, 0);
                    if (pb < 2)
                        acc[mt][nt] = __builtin_amdgcn_mfma_f32_16x16x32_bf16(Af[2][mt], Bf[nt], acc[mt][nt], 0, 0, 0);
                }
        }
    }

#pragma unroll
    for (int mt = 0; mt < 4; ++mt)
#pragma unroll
        for (int nt = 0; nt < 4; ++nt) {
            int grow = bm + wrow * 64 + mt * 16 + quad * 4;
            int gcol = bn + wcol * 64 + nt * 16 + l15;
            float* hp = H + (size_t)grow * N + gcol;
#pragma unroll
            for (int r = 0; r < 4; ++r) hp[(size_t)r * N] = acc[mt][nt][r];
        }
}

// ---------------------------------------------------------------------------
// d = w^T w   (fp32 exact-class).
// ---------------------------------------------------------------------------
__global__ __launch_bounds__(256) void gemm_wtw(const float* __restrict__ W,
                                                float* __restrict__ D) {
    const int K = I_, N = O_;
    __shared__ float As[32][68];
    __shared__ float Bs[32][68];
    const int tid = threadIdx.x;
    const int tx = tid & 15, ty = tid >> 4;
    const int bj = blockIdx.x * 64, bo = blockIdx.y * 64;
    const int lr = tid >> 4;
    const int lc = (tid & 15) << 2;

    float acc[4][4];
#pragma unroll
    for (int m = 0; m < 4; m++)
#pragma unroll
        for (int n = 0; n < 4; n++) acc[m][n] = 0.f;

    for (int k0 = 0; k0 < K; k0 += 32) {
        float4 a0 = *(const float4*)(W + (size_t)(k0 + lr) * N + bj + lc);
        float4 a1 = *(const float4*)(W + (size_t)(k0 + lr + 16) * N + bj + lc);
        float4 b0 = *(const float4*)(W + (size_t)(k0 + lr) * N + bo + lc);
        float4 b1 = *(const float4*)(W + (size_t)(k0 + lr + 16) * N + bo + lc);
        __syncthreads();
        *(float4*)&As[lr][lc] = a0; *(float4*)&As[lr + 16][lc] = a1;
        *(float4*)&Bs[lr][lc] = b0; *(float4*)&Bs[lr + 16][lc] = b1;
        __syncthreads();
#pragma unroll
        for (int k = 0; k < 32; ++k) {
            float4 av = *(const float4*)&As[k][ty * 4];
            float4 bv = *(const float4*)&Bs[k][tx * 4];
            float am[4] = {av.x, av.y, av.z, av.w};
            float bb[4] = {bv.x, bv.y, bv.z, bv.w};
#pragma unroll
            for (int m = 0; m < 4; m++)
#pragma unroll
                for (int n = 0; n < 4; n++) acc[m][n] += am[m] * bb[n];
        }
    }
#pragma unroll
    for (int m = 0; m < 4; m++) {
        float4 v = make_float4(acc[m][0], acc[m][1], acc[m][2], acc[m][3]);
        *(float4*)(D + (size_t)(bj + ty * 4 + m) * N + bo + tx * 4) = v;
    }
}

// inv_norm[o] = 1/(d[o][o] + 1e-8); zero the spike counter AND the padding
// row d[ZROW][*] used by the branch-free scan gather (ws is 0xAA-poisoned).
__global__ void colnorm_diag(const float* __restrict__ D, float* __restrict__ invn,
                             float* __restrict__ zrow,
                             unsigned int* __restrict__ counter) {
    int o = blockIdx.x * 256 + threadIdx.x;
    if (o == 0) *counter = 0u;
    zrow[o] = 0.0f;
    invn[o] = 1.0f / (D[(size_t)o * O_ + o] + 1e-8f);
}

// ---------------------------------------------------------------------------
// Sequential scan. r9: BRANCH-FREE wide gather. n is block-uniform; chunks
// of 16 with index select (v_cndmask) to the zero row for i>=n:
//   all 16 ds_reads unconditional (one lgkm wait),
//   all 16 dwordx4 gathers unconditional & back-to-back (one vm wait),
//   accumulation unconditional (zero rows add 0 -- cannot affect >0 tests).
// r8 lesson: uniform branches around each load cost more than the loads.
// Depth-2 h prefetch hides the ~900cyc HBM latency of h(t+2) behind 2 steps.
// ---------------------------------------------------------------------------
__global__ __launch_bounds__(256) void scan_kernel(const float* __restrict__ h,
                                                   const float* __restrict__ d,
                                                   const float* __restrict__ invn,
                                                   const float* __restrict__ bias,
                                                   const float* __restrict__ beta,
                                                   float* __restrict__ out,
                                                   unsigned int* __restrict__ spike_count) {
    __shared__ int lst[2][O_];
    __shared__ int cnt[T_ + 1];
    __shared__ unsigned int red[256];

    const int tid = threadIdx.x;
    const int lane = tid & 63;
    const int b = blockIdx.x;
    const int o4 = tid * 4;
    const float betav = beta[0];
    const float omb = 1.0f - betav;

    const float4 invn4 = *(const float4*)(invn + o4);
    const float4 b4 = *(const float4*)(bias + o4);
    float4 mem4 = make_float4(0.f, 0.f, 0.f, 0.f);

    for (int i = tid; i <= T_; i += 256) cnt[i] = 0;
    unsigned int local_count = 0;
    const float* hb = h + (size_t)b * T_ * O_;
    float* ob = out + (size_t)b * T_ * O_;
    const unsigned long long below = (lane == 63) ? 0xFFFFFFFFFFFFFFFFull >> 1
                                                  : ((1ull << lane) - 1ull);

    float4 hcur = *(const float4*)(hb + o4);                    // t = 0
    float4 hnext = *(const float4*)(hb + (size_t)O_ + o4);      // t = 1
    __syncthreads();

    for (int t = 0; t < T_; ++t) {
        const int p = t & 1, q = p ^ 1;
        const int n = cnt[t];                  // block-uniform

        float4 hnn = make_float4(0.f, 0.f, 0.f, 0.f);
        if (t + 2 < T_) hnn = *(const float4*)(hb + (size_t)(t + 2) * O_ + o4);

        float4 rst = make_float4(0.f, 0.f, 0.f, 0.f);
        for (int i0 = 0; i0 < n; i0 += 16) {
            int jj[16];
#pragma unroll
            for (int u = 0; u < 16; ++u) {
                int ii = i0 + u;
                int j = lst[p][ii & (O_ - 1)];   // always-valid ds_read
                jj[u] = (ii < n) ? j : ZROW;     // v_cndmask, no branch
            }
            float4 v[16];
#pragma unroll
            for (int u = 0; u < 16; ++u)
                v[u] = *(const float4*)(d + (size_t)jj[u] * O_ + o4);
#pragma unroll
            for (int u = 0; u < 16; ++u) {
                rst.x += v[u].x; rst.y += v[u].y;
                rst.z += v[u].z; rst.w += v[u].w;
            }
        }

        mem4.x = (mem4.x - rst.x) * betav + hcur.x * omb;
        mem4.y = (mem4.y - rst.y) * betav + hcur.y * omb;
        mem4.z = (mem4.z - rst.z) * betav + hcur.z * omb;
        mem4.w = (mem4.w - rst.w) * betav + hcur.w * omb;

        const int s[4] = {(mem4.x * invn4.x - b4.x) > 0.0f,
                          (mem4.y * invn4.y - b4.y) > 0.0f,
                          (mem4.z * invn4.z - b4.z) > 0.0f,
                          (mem4.w * invn4.w - b4.w) > 0.0f};

        float4 sv = make_float4(s[0] ? 1.f : 0.f, s[1] ? 1.f : 0.f,
                                s[2] ? 1.f : 0.f, s[3] ? 1.f : 0.f);
        *(float4*)(ob + (size_t)t * O_ + o4) = sv;
        local_count += (unsigned)(s[0] + s[1] + s[2] + s[3]);

        // ballot-aggregated appends into lst[q] / cnt[t+1]
#pragma unroll
        for (int u = 0; u < 4; ++u) {
            unsigned long long mask = __ballot(s[u]);
            int base = 0;
            if (lane == 0 && mask) base = atomicAdd(&cnt[t + 1], __popcll(mask));
            base = __shfl(base, 0, 64);
            if (s[u]) lst[q][base + __popcll(mask & below)] = o4 + u;
        }

        barrier_lds_only();
        hcur = hnext;
        hnext = hnn;
    }

    red[tid] = local_count;
    __syncthreads();
    for (int st = 128; st > 0; st >>= 1) {
        if (tid < st) red[tid] += red[tid + st];
        __syncthreads();
    }
    if (tid == 0) atomicAdd(spike_count, red[0]);
}

__global__ void finalize_loss(const unsigned int* __restrict__ spike_count,
                              float* __restrict__ loss_out) {
    *loss_out = 0.5f * ((float)(*spike_count) / 16777216.0f);
}

// ---------------------------------------------------------------------------
extern "C" void kernel_launch(void* const* d_in, const int* in_sizes, int n_in,
                              void* d_out, int out_size, void* d_ws, size_t ws_size,
                              hipStream_t stream) {
    const float* x    = (const float*)d_in[0];   // [B,T,I]
    const float* w    = (const float*)d_in[1];   // [I,O]
    const float* beta = (const float*)d_in[2];   // [1]
    const float* bias = (const float*)d_in[3];   // [O]
    float* out = (float*)d_out;                  // NOUT spikes + 1 loss

    // workspace layout (~170 MB); dmat has 1025 rows (row 1024 = zero row)
    char* ws = (char*)d_ws;
    float* h    = (float*)ws;                                         // 64 MiB
    float* dmat = (float*)(ws + (size_t)67108864);                    // 4 MiB + 4 KiB
    float* invn = (float*)(ws + (size_t)71311360);                    // 4 KiB
    unsigned int* cntp = (unsigned int*)(ws + (size_t)71315456);      // 4 KiB
    unsigned short* wt_h = (unsigned short*)(ws + (size_t)71319552);  // 2 MiB
    unsigned short* wt_m = (unsigned short*)(ws + (size_t)73416704);  // 2 MiB
    unsigned short* wt_l = (unsigned short*)(ws + (size_t)75513856);  // 2 MiB
    unsigned short* x_h  = (unsigned short*)(ws + (size_t)77611008);  // 32 MiB
    unsigned short* x_m  = (unsigned short*)(ws + (size_t)111165440); // 32 MiB
    unsigned short* x_l  = (unsigned short*)(ws + (size_t)144719872); // 32 MiB

    split_x<<<M_ * I_ / 1024, 256, 0, stream>>>(x, x_h, x_m, x_l);
    split_wt<<<dim3(I_ / 64, O_ / 64), 256, 0, stream>>>(w, wt_h, wt_m, wt_l);
    gemm_h_mfma<<<dim3(M_ / 128, O_ / 128), 256, 0, stream>>>(x_h, x_m, x_l,
                                                              wt_h, wt_m, wt_l, h);
    gemm_wtw<<<dim3(O_ / 64, O_ / 64), 256, 0, stream>>>(w, dmat);
    colnorm_diag<<<O_ / 256, 256, 0, stream>>>(dmat, invn, dmat + (size_t)ZROW * O_, cntp);
    scan_kernel<<<B_, 256, 0, stream>>>(h, dmat, invn, bias, beta, out, cntp);
    finalize_loss<<<1, 1, 0, stream>>>(cntp, out + (size_t)NOUT);
}

// Round 10
// 545.277 us; speedup vs baseline: 1.0244x; 1.0000x over previous
//
#include <hip/hip_runtime.h>

#define B_ 128
#define T_ 128
#define I_ 1024
#define O_ 1024
#define M_ (B_*T_)          // 16384 rows of h
#define NOUT (M_*O_)        // 16777216 spike outputs, loss at index NOUT

typedef __attribute__((ext_vector_type(8))) short short8;   // 8 bf16 = 4 VGPR
typedef __attribute__((ext_vector_type(4))) float floatx4;  // MFMA acc

// async global->LDS, 16B per lane. LDS dest = wave-uniform base + lane*16.
__device__ __forceinline__ void gld_lds16(const void* g, void* l) {
    __builtin_amdgcn_global_load_lds((const __attribute__((address_space(1))) void*)g,
                                     (__attribute__((address_space(3))) void*)l,
                                     16, 0, 0);
}

// Workgroup barrier waiting ONLY on LDS ops (lgkmcnt(0)); does NOT drain vmcnt.
__device__ __forceinline__ void barrier_lds_only() {
    asm volatile("" ::: "memory");
    __builtin_amdgcn_s_waitcnt(0xC07F);
    __builtin_amdgcn_s_barrier();
    asm volatile("" ::: "memory");
}

// Dekker-style exact 3-way bf16 split by truncation.
__device__ __forceinline__ void split3(float x, unsigned short& h,
                                       unsigned short& m, unsigned short& l) {
    unsigned int b0 = __float_as_uint(x);
    h = (unsigned short)(b0 >> 16);
    float r1 = x - __uint_as_float(b0 & 0xFFFF0000u);
    unsigned int b1 = __float_as_uint(r1);
    m = (unsigned short)(b1 >> 16);
    float r2 = r1 - __uint_as_float(b1 & 0xFFFF0000u);
    l = (unsigned short)(__float_as_uint(r2) >> 16);
}

// ---------------------------------------------------------------------------
// split_x: x [M,K] f32 -> 3 bf16 planes, same layout. Pure memory pass.
// ---------------------------------------------------------------------------
__global__ __launch_bounds__(256) void split_x(const float* __restrict__ X,
                                               unsigned short* __restrict__ Xh,
                                               unsigned short* __restrict__ Xm,
                                               unsigned short* __restrict__ Xl) {
    size_t base = ((size_t)blockIdx.x * 256 + threadIdx.x) * 4;
    float4 v = *(const float4*)(X + base);
    ushort4 hh, mm, ll;
    split3(v.x, hh.x, mm.x, ll.x);
    split3(v.y, hh.y, mm.y, ll.y);
    split3(v.z, hh.z, mm.z, ll.z);
    split3(v.w, hh.w, mm.w, ll.w);
    *(ushort4*)(Xh + base) = hh;
    *(ushort4*)(Xm + base) = mm;
    *(ushort4*)(Xl + base) = ll;
}

// ---------------------------------------------------------------------------
// split_wt: w [K][N] f32 -> three TRANSPOSED bf16 planes wt_p[N][K].
// ---------------------------------------------------------------------------
__global__ __launch_bounds__(256) void split_wt(const float* __restrict__ W,
                                                unsigned short* __restrict__ WTh,
                                                unsigned short* __restrict__ WTm,
                                                unsigned short* __restrict__ WTl) {
    __shared__ float t[64][65];
    const int tid = threadIdx.x;
    const int tx = tid & 63, ty4 = tid >> 6;
    const int r0 = blockIdx.x * 64, c0 = blockIdx.y * 64;
#pragma unroll
    for (int j = 0; j < 16; ++j) {
        int row = j * 4 + ty4;
        t[row][tx] = W[(size_t)(r0 + row) * O_ + c0 + tx];
    }
    __syncthreads();
#pragma unroll
    for (int j = 0; j < 16; ++j) {
        int i = j * 4 + ty4;
        float v = t[tx][i];
        unsigned short h, m, l;
        split3(v, h, m, l);
        size_t off = (size_t)(c0 + i) * I_ + r0 + tx;
        WTh[off] = h; WTm[off] = m; WTl[off] = l;
    }
}

// ---------------------------------------------------------------------------
// h = x @ w, all-bf16 split MFMA (r6 structure). INSTRUMENTATION (r10):
// launched as TWO M-halves (~102us each) so every dispatch >102us becomes
// visible in rocprof top-5 (r7-r9: the 204us monolith hid the scan).
// ---------------------------------------------------------------------------
__global__ __launch_bounds__(256, 3) void gemm_h_mfma(
        const unsigned short* __restrict__ Xh, const unsigned short* __restrict__ Xm,
        const unsigned short* __restrict__ Xl, const unsigned short* __restrict__ WTh,
        const unsigned short* __restrict__ WTm, const unsigned short* __restrict__ WTl,
        float* __restrict__ H, int bmBase) {
    const int K = I_, N = O_;
    __shared__ unsigned short P[6][128 * 32];   // 6 planes x 8 KB = 48 KB

    const int tid = threadIdx.x;
    const int lane = tid & 63;
    const int wid = tid >> 6;
    const int wrow = wid >> 1, wcol = wid & 1;
    const int l15 = lane & 15, quad = lane >> 4;
    const int bm = bmBase + blockIdx.x * 128, bn = blockIdx.y * 128;

    const int srow = tid >> 2, sch = tid & 3;
    const int schg = sch ^ ((srow >> 1) & 3);
    const unsigned short* gsrc[6];
    gsrc[0] = Xh  + (size_t)(bm + srow) * K + schg * 8;
    gsrc[1] = Xm  + (size_t)(bm + srow) * K + schg * 8;
    gsrc[2] = Xl  + (size_t)(bm + srow) * K + schg * 8;
    gsrc[3] = WTh + (size_t)(bn + srow) * K + schg * 8;
    gsrc[4] = WTm + (size_t)(bn + srow) * K + schg * 8;
    gsrc[5] = WTl + (size_t)(bn + srow) * K + schg * 8;

    floatx4 acc[4][4];
#pragma unroll
    for (int mt = 0; mt < 4; ++mt)
#pragma unroll
        for (int nt = 0; nt < 4; ++nt) acc[mt][nt] = (floatx4)(0.f);

    for (int kt = 0; kt < 32; ++kt) {
        const int k0 = kt * 32;
        __syncthreads();
#pragma unroll
        for (int p = 0; p < 6; ++p) {
            unsigned short* dst = (unsigned short*)P + p * 4096 + tid * 8;
            gld_lds16(gsrc[p] + k0, dst);
            gld_lds16(gsrc[p] + (size_t)64 * K + k0, dst + 2048);
        }
        __syncthreads();

        short8 Af[3][4];
#pragma unroll
        for (int pa = 0; pa < 3; ++pa)
#pragma unroll
            for (int mt = 0; mt < 4; ++mt) {
                int row = wrow * 64 + mt * 16 + l15;
                int chk = quad ^ ((row >> 1) & 3);
                Af[pa][mt] = *(const short8*)((const unsigned short*)P + pa * 4096 + row * 32 + chk * 8);
            }
#pragma unroll
        for (int pb = 0; pb < 3; ++pb) {
            short8 Bf[4];
#pragma unroll
            for (int nt = 0; nt < 4; ++nt) {
                int col = wcol * 64 + nt * 16 + l15;
                int chk = quad ^ ((col >> 1) & 3);
                Bf[nt] = *(const short8*)((const unsigned short*)P + (3 + pb) * 4096 + col * 32 + chk * 8);
            }
#pragma unroll
            for (int nt = 0; nt < 4; ++nt)
#pragma unroll
                for (int mt = 0; mt < 4; ++mt) {
                    acc[mt][nt] = __builtin_amdgcn_mfma_f32_16x16x32_bf16(Af[0][mt], Bf[nt], acc[mt][nt], 0, 0, 0);
                    acc[mt][nt] = __builtin_amdgcn_mfma_f32_16x16x32_bf16(Af[1][mt], Bf[nt], acc[mt][nt], 0, 0, 0);
                    if (pb < 2)
                        acc[mt][nt] = __builtin_amdgcn_mfma_f32_16x16x32_bf16(Af[2][mt], Bf[nt], acc[mt][nt], 0, 0, 0);
                }
        }
    }

#pragma unroll
    for (int mt = 0; mt < 4; ++mt)
#pragma unroll
        for (int nt = 0; nt < 4; ++nt) {
            int grow = bm + wrow * 64 + mt * 16 + quad * 4;
            int gcol = bn + wcol * 64 + nt * 16 + l15;
            float* hp = H + (size_t)grow * N + gcol;
#pragma unroll
            for (int r = 0; r < 4; ++r) hp[(size_t)r * N] = acc[mt][nt][r];
        }
}

// ---------------------------------------------------------------------------
// d = w^T w   (fp32 exact-class).
// ---------------------------------------------------------------------------
__global__ __launch_bounds__(256) void gemm_wtw(const float* __restrict__ W,
                                                float* __restrict__ D) {
    const int K = I_, N = O_;
    __shared__ float As[32][68];
    __shared__ float Bs[32][68];
    const int tid = threadIdx.x;
    const int tx = tid & 15, ty = tid >> 4;
    const int bj = blockIdx.x * 64, bo = blockIdx.y * 64;
    const int lr = tid >> 4;
    const int lc = (tid & 15) << 2;

    float acc[4][4];
#pragma unroll
    for (int m = 0; m < 4; m++)
#pragma unroll
        for (int n = 0; n < 4; n++) acc[m][n] = 0.f;

    for (int k0 = 0; k0 < K; k0 += 32) {
        float4 a0 = *(const float4*)(W + (size_t)(k0 + lr) * N + bj + lc);
        float4 a1 = *(const float4*)(W + (size_t)(k0 + lr + 16) * N + bj + lc);
        float4 b0 = *(const float4*)(W + (size_t)(k0 + lr) * N + bo + lc);
        float4 b1 = *(const float4*)(W + (size_t)(k0 + lr + 16) * N + bo + lc);
        __syncthreads();
        *(float4*)&As[lr][lc] = a0; *(float4*)&As[lr + 16][lc] = a1;
        *(float4*)&Bs[lr][lc] = b0; *(float4*)&Bs[lr + 16][lc] = b1;
        __syncthreads();
#pragma unroll
        for (int k = 0; k < 32; ++k) {
            float4 av = *(const float4*)&As[k][ty * 4];
            float4 bv = *(const float4*)&Bs[k][tx * 4];
            float am[4] = {av.x, av.y, av.z, av.w};
            float bb[4] = {bv.x, bv.y, bv.z, bv.w};
#pragma unroll
            for (int m = 0; m < 4; m++)
#pragma unroll
                for (int n = 0; n < 4; n++) acc[m][n] += am[m] * bb[n];
        }
    }
#pragma unroll
    for (int m = 0; m < 4; m++) {
        float4 v = make_float4(acc[m][0], acc[m][1], acc[m][2], acc[m][3]);
        *(float4*)(D + (size_t)(bj + ty * 4 + m) * N + bo + tx * 4) = v;
    }
}

// inv_norm[o] = 1/(d[o][o] + 1e-8); also zero the spike counter.
__global__ void colnorm_diag(const float* __restrict__ D, float* __restrict__ invn,
                             unsigned int* __restrict__ counter) {
    int o = blockIdx.x * 256 + threadIdx.x;
    if (o == 0) *counter = 0u;
    invn[o] = 1.0f / (D[(size_t)o * O_ + o] + 1e-8f);
}

// ---------------------------------------------------------------------------
// Sequential scan: r7-best gather (16-batch + 4-batch + singles), with n made
// SCALAR via readfirstlane (r8 lesson: branch bookkeeping on vector n costs).
// One LDS-only barrier per step; depth-2 h prefetch.
// ---------------------------------------------------------------------------
__global__ __launch_bounds__(256) void scan_kernel(const float* __restrict__ h,
                                                   const float* __restrict__ d,
                                                   const float* __restrict__ invn,
                                                   const float* __restrict__ bias,
                                                   const float* __restrict__ beta,
                                                   float* __restrict__ out,
                                                   unsigned int* __restrict__ spike_count) {
    __shared__ int lst[2][O_];
    __shared__ int cnt[T_ + 1];
    __shared__ unsigned int red[256];

    const int tid = threadIdx.x;
    const int lane = tid & 63;
    const int b = blockIdx.x;
    const int o4 = tid * 4;
    const float betav = beta[0];
    const float omb = 1.0f - betav;

    const float4 invn4 = *(const float4*)(invn + o4);
    const float4 b4 = *(const float4*)(bias + o4);
    float4 mem4 = make_float4(0.f, 0.f, 0.f, 0.f);

    for (int i = tid; i <= T_; i += 256) cnt[i] = 0;
    unsigned int local_count = 0;
    const float* hb = h + (size_t)b * T_ * O_;
    float* ob = out + (size_t)b * T_ * O_;
    const unsigned long long below = (lane == 63) ? 0xFFFFFFFFFFFFFFFFull >> 1
                                                  : ((1ull << lane) - 1ull);

    float4 hcur = *(const float4*)(hb + o4);                    // t = 0
    float4 hnext = *(const float4*)(hb + (size_t)O_ + o4);      // t = 1
    __syncthreads();

    for (int t = 0; t < T_; ++t) {
        const int p = t & 1, q = p ^ 1;
        const int n = __builtin_amdgcn_readfirstlane(cnt[t]);   // scalar bound

        float4 hnn = make_float4(0.f, 0.f, 0.f, 0.f);
        if (t + 2 < T_) hnn = *(const float4*)(hb + (size_t)(t + 2) * O_ + o4);

        float4 rst = make_float4(0.f, 0.f, 0.f, 0.f);
        int i = 0;
        for (; i + 16 <= n; i += 16) {
            float4 v[16];
#pragma unroll
            for (int u = 0; u < 16; ++u) {
                const int j = lst[p][i + u];
                v[u] = *(const float4*)(d + (size_t)j * O_ + o4);
            }
#pragma unroll
            for (int u = 0; u < 16; ++u) {
                rst.x += v[u].x; rst.y += v[u].y;
                rst.z += v[u].z; rst.w += v[u].w;
            }
        }
        for (; i + 4 <= n; i += 4) {
            float4 v[4];
#pragma unroll
            for (int u = 0; u < 4; ++u) {
                const int j = lst[p][i + u];
                v[u] = *(const float4*)(d + (size_t)j * O_ + o4);
            }
#pragma unroll
            for (int u = 0; u < 4; ++u) {
                rst.x += v[u].x; rst.y += v[u].y;
                rst.z += v[u].z; rst.w += v[u].w;
            }
        }
        for (; i < n; ++i) {
            const int j = lst[p][i];
            float4 v = *(const float4*)(d + (size_t)j * O_ + o4);
            rst.x += v.x; rst.y += v.y; rst.z += v.z; rst.w += v.w;
        }

        mem4.x = (mem4.x - rst.x) * betav + hcur.x * omb;
        mem4.y = (mem4.y - rst.y) * betav + hcur.y * omb;
        mem4.z = (mem4.z - rst.z) * betav + hcur.z * omb;
        mem4.w = (mem4.w - rst.w) * betav + hcur.w * omb;

        const int s[4] = {(mem4.x * invn4.x - b4.x) > 0.0f,
                          (mem4.y * invn4.y - b4.y) > 0.0f,
                          (mem4.z * invn4.z - b4.z) > 0.0f,
                          (mem4.w * invn4.w - b4.w) > 0.0f};

        float4 sv = make_float4(s[0] ? 1.f : 0.f, s[1] ? 1.f : 0.f,
                                s[2] ? 1.f : 0.f, s[3] ? 1.f : 0.f);
        *(float4*)(ob + (size_t)t * O_ + o4) = sv;
        local_count += (unsigned)(s[0] + s[1] + s[2] + s[3]);

        // ballot-aggregated appends into lst[q] / cnt[t+1]
#pragma unroll
        for (int u = 0; u < 4; ++u) {
            unsigned long long mask = __ballot(s[u]);
            int base = 0;
            if (lane == 0 && mask) base = atomicAdd(&cnt[t + 1], __popcll(mask));
            base = __shfl(base, 0, 64);
            if (s[u]) lst[q][base + __popcll(mask & below)] = o4 + u;
        }

        barrier_lds_only();
        hcur = hnext;
        hnext = hnn;
    }

    red[tid] = local_count;
    __syncthreads();
    for (int st = 128; st > 0; st >>= 1) {
        if (tid < st) red[tid] += red[tid + st];
        __syncthreads();
    }
    if (tid == 0) atomicAdd(spike_count, red[0]);
}

__global__ void finalize_loss(const unsigned int* __restrict__ spike_count,
                              float* __restrict__ loss_out) {
    *loss_out = 0.5f * ((float)(*spike_count) / 16777216.0f);
}

// ---------------------------------------------------------------------------
extern "C" void kernel_launch(void* const* d_in, const int* in_sizes, int n_in,
                              void* d_out, int out_size, void* d_ws, size_t ws_size,
                              hipStream_t stream) {
    const float* x    = (const float*)d_in[0];   // [B,T,I]
    const float* w    = (const float*)d_in[1];   // [I,O]
    const float* beta = (const float*)d_in[2];   // [1]
    const float* bias = (const float*)d_in[3];   // [O]
    float* out = (float*)d_out;                  // NOUT spikes + 1 loss

    // workspace layout (~170 MB)
    char* ws = (char*)d_ws;
    float* h    = (float*)ws;                                         // 64 MiB
    float* dmat = (float*)(ws + (size_t)67108864);                    // 4 MiB
    float* invn = (float*)(ws + (size_t)71311360);                    // 4 KiB
    unsigned int* cntp = (unsigned int*)(ws + (size_t)71315456);      // 4 KiB
    unsigned short* wt_h = (unsigned short*)(ws + (size_t)71319552);  // 2 MiB
    unsigned short* wt_m = (unsigned short*)(ws + (size_t)73416704);  // 2 MiB
    unsigned short* wt_l = (unsigned short*)(ws + (size_t)75513856);  // 2 MiB
    unsigned short* x_h  = (unsigned short*)(ws + (size_t)77611008);  // 32 MiB
    unsigned short* x_m  = (unsigned short*)(ws + (size_t)111165440); // 32 MiB
    unsigned short* x_l  = (unsigned short*)(ws + (size_t)144719872); // 32 MiB

    split_x<<<M_ * I_ / 1024, 256, 0, stream>>>(x, x_h, x_m, x_l);
    split_wt<<<dim3(I_ / 64, O_ / 64), 256, 0, stream>>>(w, wt_h, wt_m, wt_l);
    // two M-halves: instrumentation (each ~102us -> frees top-5 slots)
    gemm_h_mfma<<<dim3(M_ / 256, O_ / 128), 256, 0, stream>>>(x_h, x_m, x_l,
                                                              wt_h, wt_m, wt_l, h, 0);
    gemm_h_mfma<<<dim3(M_ / 256, O_ / 128), 256, 0, stream>>>(x_h, x_m, x_l,
                                                              wt_h, wt_m, wt_l, h, M_ / 2);
    gemm_wtw<<<dim3(O_ / 64, O_ / 64), 256, 0, stream>>>(w, dmat);
    colnorm_diag<<<O_ / 256, 256, 0, stream>>>(dmat, invn, cntp);
    scan_kernel<<<B_, 256, 0, stream>>>(h, dmat, invn, bias, beta, out, cntp);
    finalize_loss<<<1, 1, 0, stream>>>(cntp, out + (size_t)NOUT);
}